// Round 11
// baseline (278.708 us; speedup 1.0000x reference)
//
#include <hip/hip_runtime.h>

// SimVQ: x[8,2048,512] f32, codebook[8192,512] f32, W[512,512] f32
// out = concat(quantized[16384*512], indices[16384] (as f32), commit_loss[1])
//
// Round 17 (from R16 = 274.5; d2 = 143.7 stable; tail noisy +-5-10us across
// sessions — only structural levers are measurable):
//  T4 counted-vmcnt pipeline in d2 + codes: 3-buffer rotation, raw
//  __builtin_amdgcn_s_barrier() + s_waitcnt vmcnt(N) (N = next stage's loads
//  stay IN FLIGHT across the barrier; __syncthreads would drain vmcnt(0)).
//  Each wave waits its own older loads, then barrier -> staged data visible.
//  d2: 48KB LDS (3 bufs), still 3 blocks/CU. codes: 96KB, 1 block/CU (the
//  kernel with zero cross-block hiding benefits most).
//  Unchanged: emission, refine (R12 serial), prep, finalize, d2 setprio.

#define DIMK  512
#define CBN   8192
#define MROWS 16384

#define SX 24.0f
#define SC 500.0f
#define INV_SS (1.0f / (SX * SC))
#define DKEY  1231
#define NSLOT 3

// ws layout (bytes)
#define WS_CODES   0UL          // 8192*512*4    = 16,777,216
#define WS_XQ      16777216UL   // 16384*512     =  8,388,608
#define WS_CQ      25165824UL   // 8192*512      =  4,194,304
#define WS_NORMS   29360128UL   // 8192*4
#define WS_CAND    29392896UL   // 16384*128*3*4 = 25,165,824
#define WS_CBH     29392896UL   // alias: cb hi (consumed before d2 writes cand)
#define WS_CBL     37781504UL   // alias: cb lo
#define WS_WH      54558720UL   // 512*512*2 = 524,288
#define WS_WL      55083008UL
#define WS_LOSSP   55607296UL   // 16384*4
// end ~55.7 MB

typedef short s16x8 __attribute__((ext_vector_type(8)));
typedef int   i32x4 __attribute__((ext_vector_type(4)));
typedef float f32x4 __attribute__((ext_vector_type(4)));

__device__ __forceinline__ unsigned short f2bf(float f) {
    unsigned u = __float_as_uint(f);
    unsigned r = u + 0x7FFFu + ((u >> 16) & 1u);   // RTNE
    return (unsigned short)(r >> 16);
}
__device__ __forceinline__ float bf2f(unsigned short h) {
    return __uint_as_float(((unsigned)h) << 16);
}
__device__ __forceinline__ void load_lds16(const void* g, void* l) {
    __builtin_amdgcn_global_load_lds((const __attribute__((address_space(1))) void*)g,
                                     (__attribute__((address_space(3))) void*)l,
                                     16, 0, 0);
}
__device__ __forceinline__ signed char q8(float v, float s) {
    return (signed char)__float2int_rn(fminf(fmaxf(v * s, -127.0f), 127.0f));
}

// counted-vmcnt barrier: wait until <=N of this wave's VMEM ops outstanding,
// then block barrier. All waves having waited their own older loads + barrier
// => all older staged data visible. Raw barrier (NOT __syncthreads, which
// emits vmcnt(0) and drains the pipeline).
#define WAIT_BAR(N)                                              \
    do {                                                         \
        asm volatile("s_waitcnt vmcnt(" #N ")" ::: "memory");    \
        __builtin_amdgcn_s_barrier();                            \
        asm volatile("" ::: "memory");                           \
    } while (0)

// ---------- fused prep: quant_x + split(cb) + split(W) + norms zero ----------
__global__ __launch_bounds__(256) void prep(
        const float* __restrict__ x, const float* __restrict__ cb, const float* __restrict__ W,
        signed char* __restrict__ xq,
        unsigned short* __restrict__ cbh, unsigned short* __restrict__ cbl,
        unsigned short* __restrict__ wh, unsigned short* __restrict__ wl,
        float* __restrict__ norms) {
    const int b = blockIdx.x;
    const int t = threadIdx.x;
    if (b < 8192) {
        const int i = b * 256 + t;
        float4 v = ((const float4*)x)[i];
        char4 c;
        c.x = q8(v.x, SX); c.y = q8(v.y, SX); c.z = q8(v.z, SX); c.w = q8(v.w, SX);
        ((char4*)xq)[i] = c;
    } else if (b < 12288) {
        const int i = (b - 8192) * 256 + t;
        float4 v = ((const float4*)cb)[i];
        ushort4 h, l;
        h.x = f2bf(v.x); l.x = f2bf(v.x - bf2f(h.x));
        h.y = f2bf(v.y); l.y = f2bf(v.y - bf2f(h.y));
        h.z = f2bf(v.z); l.z = f2bf(v.z - bf2f(h.z));
        h.w = f2bf(v.w); l.w = f2bf(v.w - bf2f(h.w));
        ((ushort4*)cbh)[i] = h;
        ((ushort4*)cbl)[i] = l;
    } else if (b < 12544) {
        const int i = (b - 12288) * 256 + t;
        float4 v = ((const float4*)W)[i];
        ushort4 h, l;
        h.x = f2bf(v.x); l.x = f2bf(v.x - bf2f(h.x));
        h.y = f2bf(v.y); l.y = f2bf(v.y - bf2f(h.y));
        h.z = f2bf(v.z); l.z = f2bf(v.z - bf2f(h.z));
        h.w = f2bf(v.w); l.w = f2bf(v.w - bf2f(h.w));
        ((ushort4*)wh)[i] = h;
        ((ushort4*)wl)[i] = l;
    } else {
        const int i = (b - 12544) * 256 + t;   // 0..8191
        norms[i] = 0.0f;
    }
}

// ------ codes = cb @ W^T via bf16 hi/lo 3-pass MFMA; emit f32 + i8 + norms ------
// grid (64,4), 512 thr = 8 waves (wm 0..3 x wn 0..1), wave tile 32x64, acc[2][4].
// Swizzled LDS, 3-deep counted-vmcnt pipeline (16 K-steps of 32).
__global__ __launch_bounds__(512) void codes_mfma(
        const unsigned short* __restrict__ Ah_g, const unsigned short* __restrict__ Al_g,
        const unsigned short* __restrict__ Bh_g, const unsigned short* __restrict__ Bl_g,
        float* __restrict__ C, signed char* __restrict__ Cq, float* __restrict__ Norms) {
    __shared__ __align__(16) unsigned short Ahi[3][128 * 32];
    __shared__ __align__(16) unsigned short Alo[3][128 * 32];
    __shared__ __align__(16) unsigned short Bhi[3][128 * 32];
    __shared__ __align__(16) unsigned short Blo[3][128 * 32];

    const int t    = threadIdx.x;
    const int w    = t >> 6;
    const int lane = t & 63;
    const int quad = lane >> 4;
    const int l16  = lane & 15;
    const int wm   = w & 3, wn = w >> 2;
    const int rowBase = blockIdx.x * 128;
    const int colBase = blockIdx.y * 128;

    f32x4 acc[2][4];
    #pragma unroll
    for (int i = 0; i < 2; ++i)
        #pragma unroll
        for (int j = 0; j < 4; ++j)
            acc[i][j] = (f32x4)(0.0f);

    const int mr = t >> 2;                             // 0..127
    const int kq = ((t & 3) ^ ((t >> 3) & 3)) * 8;     // swizzled source chunk (ushorts)
    const size_t gxa = (size_t)(rowBase + mr) * DIMK + kq;
    const size_t gca = (size_t)(colBase + mr) * DIMK + kq;
    const int l0 = w * 512;                            // wave-uniform LDS ushort base

    const int swz8 = (quad ^ ((l16 >> 1) & 3)) * 8;    // swizzled read chunk (ushorts)

#define CODES_STAGE(B, K0)                                     \
    do {                                                       \
        load_lds16(Ah_g + gxa + (K0), &Ahi[B][l0]);            \
        load_lds16(Al_g + gxa + (K0), &Alo[B][l0]);            \
        load_lds16(Bh_g + gca + (K0), &Bhi[B][l0]);            \
        load_lds16(Bl_g + gca + (K0), &Blo[B][l0]);            \
    } while (0)

#define CODES_COMPUTE(CUR)                                                                         \
    do {                                                                                           \
        s16x8 ah[2], al[2], bh[4], bl[4];                                                          \
        _Pragma("unroll")                                                                          \
        for (int i = 0; i < 2; ++i) {                                                              \
            const int m = wm * 32 + i * 16 + l16;                                                  \
            ah[i] = *(const s16x8*)&Ahi[CUR][m * 32 + swz8];                                       \
            al[i] = *(const s16x8*)&Alo[CUR][m * 32 + swz8];                                       \
        }                                                                                          \
        _Pragma("unroll")                                                                          \
        for (int j = 0; j < 4; ++j) {                                                              \
            const int n = wn * 64 + j * 16 + l16;                                                  \
            bh[j] = *(const s16x8*)&Bhi[CUR][n * 32 + swz8];                                       \
            bl[j] = *(const s16x8*)&Blo[CUR][n * 32 + swz8];                                       \
        }                                                                                          \
        _Pragma("unroll")                                                                          \
        for (int i = 0; i < 2; ++i)                                                                \
            _Pragma("unroll")                                                                      \
            for (int j = 0; j < 4; ++j) {                                                          \
                acc[i][j] = __builtin_amdgcn_mfma_f32_16x16x32_bf16(ah[i], bh[j], acc[i][j], 0, 0, 0); \
                acc[i][j] = __builtin_amdgcn_mfma_f32_16x16x32_bf16(ah[i], bl[j], acc[i][j], 0, 0, 0); \
                acc[i][j] = __builtin_amdgcn_mfma_f32_16x16x32_bf16(al[i], bh[j], acc[i][j], 0, 0, 0); \
            }                                                                                      \
    } while (0)

    // 3-deep pipeline: stage t+2 while computing t; vmcnt(4) leaves the newest
    // stage's 4 loads in flight across the barrier.
    CODES_STAGE(0, 0);
    CODES_STAGE(1, 32);
    WAIT_BAR(4);                       // step0 data visible

    CODES_STAGE(2,  64); CODES_COMPUTE(0); WAIT_BAR(4);
    CODES_STAGE(0,  96); CODES_COMPUTE(1); WAIT_BAR(4);
    CODES_STAGE(1, 128); CODES_COMPUTE(2); WAIT_BAR(4);
    CODES_STAGE(2, 160); CODES_COMPUTE(0); WAIT_BAR(4);
    CODES_STAGE(0, 192); CODES_COMPUTE(1); WAIT_BAR(4);
    CODES_STAGE(1, 224); CODES_COMPUTE(2); WAIT_BAR(4);
    CODES_STAGE(2, 256); CODES_COMPUTE(0); WAIT_BAR(4);
    CODES_STAGE(0, 288); CODES_COMPUTE(1); WAIT_BAR(4);
    CODES_STAGE(1, 320); CODES_COMPUTE(2); WAIT_BAR(4);
    CODES_STAGE(2, 352); CODES_COMPUTE(0); WAIT_BAR(4);
    CODES_STAGE(0, 384); CODES_COMPUTE(1); WAIT_BAR(4);
    CODES_STAGE(1, 416); CODES_COMPUTE(2); WAIT_BAR(4);
    CODES_STAGE(2, 448); CODES_COMPUTE(0); WAIT_BAR(4);
    CODES_STAGE(0, 480); CODES_COMPUTE(1); WAIT_BAR(4);
    CODES_COMPUTE(2);                   WAIT_BAR(0);   // drain last stage
    CODES_COMPUTE(0);
#undef CODES_STAGE
#undef CODES_COMPUTE

    // epilogue: C/D layout col = j*16+l16, row = i*16+quad*4+r
    #pragma unroll
    for (int i = 0; i < 2; ++i) {
        #pragma unroll
        for (int r = 0; r < 4; ++r) {
            const int row = rowBase + wm * 32 + i * 16 + quad * 4 + r;
            float nsum = 0.0f;
            #pragma unroll
            for (int j = 0; j < 4; ++j) {
                const int col = colBase + wn * 64 + j * 16 + l16;
                const float v = acc[i][j][r];
                C[(size_t)row * DIMK + col] = v;
                Cq[(size_t)row * DIMK + col] = q8(v, SC);
                nsum = fmaf(v, v, nsum);
            }
            nsum += __shfl_xor(nsum, 1, 64);
            nsum += __shfl_xor(nsum, 2, 64);
            nsum += __shfl_xor(nsum, 4, 64);
            nsum += __shfl_xor(nsum, 8, 64);
            if (l16 == 0) atomicAdd(&Norms[row], nsum);
        }
    }
}

// ---------- i8 distance GEMM (MFMA 16x16x64) + branch-free top-3 emission ----------
// grid: (MROWS/128, CBN/128), 512 threads = 8 waves (4x2), wave tile 32x64 (acc 2x4).
// Swizzled LDS, 3-deep counted-vmcnt pipeline (8 K-steps of 64), setprio on MFMA.
// LDS 48KB -> 3 blocks/CU.
__global__ __launch_bounds__(512, 6) void d2_argmin_i8(
        const signed char* __restrict__ Xq,
        const signed char* __restrict__ Cq,
        const float* __restrict__ Norms,
        unsigned* __restrict__ Cand) {
    __shared__ __align__(16) signed char Ash[3][128 * 64];
    __shared__ __align__(16) signed char Bsh[3][128 * 64];

    const int t    = threadIdx.x;
    const int w    = t >> 6;
    const int lane = t & 63;
    const int quad = lane >> 4;
    const int l16  = lane & 15;
    const int wm   = w & 3, wn = w >> 2;
    const int rowBase = blockIdx.x * 128;
    const int colBase = blockIdx.y * 128;

    i32x4 acc[2][4];
    #pragma unroll
    for (int i = 0; i < 2; ++i)
        #pragma unroll
        for (int j = 0; j < 4; ++j)
            acc[i][j] = (i32x4)(0);

    const int mr  = t >> 2;                              // 0..127
    const int kcs = ((t & 3) ^ ((t >> 3) & 3)) * 16;     // swizzled source chunk (bytes)
    const size_t gxa = (size_t)(rowBase + mr) * DIMK + kcs;
    const size_t gca = (size_t)(colBase + mr) * DIMK + kcs;
    const int lb = w * 1024;            // wave-uniform LDS byte base

    const int swz  = (quad ^ ((l16 >> 1) & 3)) * 16;
    const int aoff = (wm * 32 + l16) * 64 + swz;
    const int boff = (wn * 64 + l16) * 64 + swz;

    // key bias per column group: nq = norm*4096 + 65536 (these global loads
    // retire before the staged loads; counted vmcnt stays conservative-safe)
    float nq[4];
    #pragma unroll
    for (int j = 0; j < 4; ++j)
        nq[j] = fmaf(Norms[colBase + wn * 64 + j * 16 + l16], 4096.0f, 65536.0f);

#define D2_STAGE(B, K0)                                        \
    do {                                                       \
        load_lds16(Xq + gxa + (K0), &Ash[B][lb]);              \
        load_lds16(Cq + gca + (K0), &Bsh[B][lb]);              \
    } while (0)

#define D2_COMPUTE(CUR)                                                                            \
    do {                                                                                           \
        i32x4 af0 = *(const i32x4*)&Ash[CUR][aoff];                                                \
        i32x4 af1 = *(const i32x4*)&Ash[CUR][aoff + 1024];                                         \
        __builtin_amdgcn_s_setprio(1);                                                             \
        _Pragma("unroll")                                                                          \
        for (int j = 0; j < 4; ++j) {                                                              \
            const i32x4 bfj = *(const i32x4*)&Bsh[CUR][boff + j * 1024];                           \
            acc[0][j] = __builtin_amdgcn_mfma_i32_16x16x64_i8(af0, bfj, acc[0][j], 0, 0, 0);       \
            acc[1][j] = __builtin_amdgcn_mfma_i32_16x16x64_i8(af1, bfj, acc[1][j], 0, 0, 0);       \
        }                                                                                          \
        __builtin_amdgcn_s_setprio(0);                                                             \
    } while (0)

    // 3-deep pipeline: stage t+2 while computing t; vmcnt(2) leaves the newest
    // stage's 2 loads in flight across the barrier.
    D2_STAGE(0, 0);
    D2_STAGE(1, 64);
    WAIT_BAR(2);                       // step0 data visible

    D2_STAGE(2, 128); D2_COMPUTE(0); WAIT_BAR(2);
    D2_STAGE(0, 192); D2_COMPUTE(1); WAIT_BAR(2);
    D2_STAGE(1, 256); D2_COMPUTE(2); WAIT_BAR(2);
    D2_STAGE(2, 320); D2_COMPUTE(0); WAIT_BAR(2);
    D2_STAGE(0, 384); D2_COMPUTE(1); WAIT_BAR(2);
    D2_STAGE(1, 448); D2_COMPUTE(2); WAIT_BAR(2);
    D2_COMPUTE(0);                   WAIT_BAR(0);   // drain k=448's loads
    D2_COMPUTE(1);
#undef D2_STAGE
#undef D2_COMPUTE

    // ---- branch-free top-3 per (row, 64-col subtile) ----
    const unsigned colG = colBase + wn * 64 + l16;
    const int subtile = blockIdx.y * 2 + wn;
    const float C2 = -8192.0f * INV_SS;

    #pragma unroll
    for (int i = 0; i < 2; ++i) {
        #pragma unroll
        for (int r = 0; r < 4; ++r) {
            unsigned k[4];
            #pragma unroll
            for (int j = 0; j < 4; ++j) {
                const float kf = fmaf((float)acc[i][j][r], C2, nq[j]);
                int ki = (int)kf;
                ki = ki < 0 ? 0 : ki;
                ki = ki > 524287 ? 524287 : ki;
                k[j] = ((unsigned)ki << 13) | (colG + j * 16);
            }
            unsigned lo01 = min(k[0], k[1]), hi01 = max(k[0], k[1]);
            unsigned lo23 = min(k[2], k[3]), hi23 = max(k[2], k[3]);
            unsigned a0 = min(lo01, lo23);
            unsigned m  = max(lo01, lo23);
            unsigned tt = min(hi01, hi23);
            unsigned a1 = min(m, tt);
            unsigned a2 = max(m, tt);
            #pragma unroll
            for (int mk = 1; mk < 16; mk <<= 1) {
                const unsigned b0 = __shfl_xor(a0, mk, 64);
                const unsigned b1 = __shfl_xor(a1, mk, 64);
                const unsigned b2 = __shfl_xor(a2, mk, 64);
                const unsigned M0 = max(a0, b0);
                const unsigned m1 = min(a1, b1);
                const unsigned n0 = min(a0, b0);
                a2 = min(max(m1, M0), min(a2, b2));
                a1 = min(M0, m1);
                a0 = n0;
            }
            if (l16 == 0) {
                const int row = rowBase + wm * 32 + i * 16 + quad * 4 + r;
                unsigned* slot = Cand + ((size_t)row * 128 + subtile) * NSLOT;
                slot[0] = a0; slot[1] = a1; slot[2] = a2;
            }
        }
    }
}

// ---------- refine candidates exactly (f32) + gather + loss partial ----------
// [R12 serial version; plain lossP store, no atomics]
__global__ __launch_bounds__(256) void refine_gather(
        const float* __restrict__ X, const float* __restrict__ Codes,
        const float* __restrict__ Norms, const unsigned* __restrict__ Cand,
        float* __restrict__ outQ, float* __restrict__ outIdx,
        float* __restrict__ lossP) {
    const int t    = threadIdx.x;
    const int w    = t >> 6;
    const int lane = t & 63;
    const int row  = blockIdx.x * 4 + w;

    const unsigned* cp = Cand + (size_t)row * 128 * NSLOT + lane * 6;
    unsigned sl[6];
    #pragma unroll
    for (int s = 0; s < 6; ++s) sl[s] = cp[s];

    unsigned mn = sl[0];
    #pragma unroll
    for (int s = 1; s < 6; ++s) mn = min(mn, sl[s]);
    #pragma unroll
    for (int mask = 1; mask < 64; mask <<= 1)
        mn = min(mn, (unsigned)__shfl((int)mn, lane ^ mask, 64));
    const unsigned thrp = (((mn >> 13) + DKEY) << 13) | 0x1FFFu;

    const float4 xa = *(const float4*)(X + (size_t)row * DIMK + lane * 8);
    const float4 xb = *(const float4*)(X + (size_t)row * DIMK + lane * 8 + 4);

    float bestD = __builtin_inff();
    unsigned bestIdx = 0xFFFFFFFFu;

    #pragma unroll
    for (int s = 0; s < 6; ++s) {
        unsigned long long bm = __ballot(sl[s] <= thrp);
        while (bm) {
            const int src = __ffsll(bm) - 1;
            bm &= bm - 1;
            const unsigned sv = (unsigned)__shfl((int)sl[s], src, 64);
            const unsigned idx = sv & 0x1FFFu;
            const float4 ca = *(const float4*)(Codes + (size_t)idx * DIMK + lane * 8);
            const float4 cbv = *(const float4*)(Codes + (size_t)idx * DIMK + lane * 8 + 4);
            float s2 = xa.x * ca.x + xa.y * ca.y + xa.z * ca.z + xa.w * ca.w
                     + xb.x * cbv.x + xb.y * cbv.y + xb.z * cbv.z + xb.w * cbv.w;
            #pragma unroll
            for (int mm = 1; mm < 64; mm <<= 1) s2 += __shfl_xor(s2, mm, 64);
            const float d2 = fmaf(-2.0f, s2, Norms[idx]);
            if (d2 < bestD || (d2 == bestD && idx < bestIdx)) { bestD = d2; bestIdx = idx; }
        }
    }

    const float4 qa = *(const float4*)(Codes + (size_t)bestIdx * DIMK + lane * 8);
    const float4 qb = *(const float4*)(Codes + (size_t)bestIdx * DIMK + lane * 8 + 4);
    *(float4*)(outQ + (size_t)row * DIMK + lane * 8) = qa;
    *(float4*)(outQ + (size_t)row * DIMK + lane * 8 + 4) = qb;
    float dx0 = xa.x - qa.x, dx1 = xa.y - qa.y, dx2 = xa.z - qa.z, dx3 = xa.w - qa.w;
    float dy0 = xb.x - qb.x, dy1 = xb.y - qb.y, dy2 = xb.z - qb.z, dy3 = xb.w - qb.w;
    float s = dx0 * dx0 + dx1 * dx1 + dx2 * dx2 + dx3 * dx3
            + dy0 * dy0 + dy1 * dy1 + dy2 * dy2 + dy3 * dy3;
    #pragma unroll
    for (int off = 32; off > 0; off >>= 1) s += __shfl_down(s, off);
    if (lane == 0) {
        lossP[row] = s;
        outIdx[row] = (float)bestIdx;
    }
}

// ---------- finalize: 1024 thr, 4 parallel float4 loads/thread ----------
__global__ __launch_bounds__(1024) void finalize_loss(const float* __restrict__ lossPartials,
                                                      float* __restrict__ outLoss) {
    const int t = threadIdx.x;
    const float4* p = (const float4*)lossPartials;   // 4096 float4s
    const float4 a = p[t];
    const float4 b = p[t + 1024];
    const float4 c = p[t + 2048];
    const float4 d = p[t + 3072];
    float s = (a.x + a.y + a.z + a.w) + (b.x + b.y + b.z + b.w)
            + (c.x + c.y + c.z + c.w) + (d.x + d.y + d.z + d.w);
    #pragma unroll
    for (int off = 32; off > 0; off >>= 1) s += __shfl_down(s, off);
    __shared__ float red[16];
    if ((t & 63) == 0) red[t >> 6] = s;
    __syncthreads();
    if (t < 64) {
        float v = (t < 16) ? red[t] : 0.0f;
        v += __shfl_down(v, 8, 64);
        v += __shfl_down(v, 4, 64);
        v += __shfl_down(v, 2, 64);
        v += __shfl_down(v, 1, 64);
        if (t == 0)
            *outLoss = v * (1.0f / (float)((size_t)MROWS * DIMK));
    }
}

extern "C" void kernel_launch(void* const* d_in, const int* in_sizes, int n_in,
                              void* d_out, int out_size, void* d_ws, size_t ws_size,
                              hipStream_t stream) {
    const float* x  = (const float*)d_in[0];
    const float* cb = (const float*)d_in[1];
    const float* W  = (const float*)d_in[2];
    float* out = (float*)d_out;

    char* ws = (char*)d_ws;
    float* codes          = (float*)(ws + WS_CODES);
    signed char* xq       = (signed char*)(ws + WS_XQ);
    signed char* cq       = (signed char*)(ws + WS_CQ);
    float* norms          = (float*)(ws + WS_NORMS);
    unsigned* cand        = (unsigned*)(ws + WS_CAND);
    unsigned short* cbh   = (unsigned short*)(ws + WS_CBH);   // aliases cand
    unsigned short* cbl   = (unsigned short*)(ws + WS_CBL);   // aliases cand
    unsigned short* wh    = (unsigned short*)(ws + WS_WH);
    unsigned short* wl    = (unsigned short*)(ws + WS_WL);
    float* lossP          = (float*)(ws + WS_LOSSP);

    // fused prep: x->i8, cb/W->bf16 hi/lo, norms zero
    prep<<<12576, 256, 0, stream>>>(x, cb, W, xq, cbh, cbl, wh, wl, norms);

    // codes = cb @ W^T (3-pass hi/lo MFMA, 3-deep counted-vmcnt pipeline)
    codes_mfma<<<dim3(CBN / 128, DIMK / 128), 512, 0, stream>>>(cbh, cbl, wh, wl, codes, cq, norms);

    // i8 MFMA distance + top-3 emission (3-deep counted-vmcnt pipeline + setprio)
    d2_argmin_i8<<<dim3(MROWS / 128, CBN / 128), 512, 0, stream>>>(xq, cq, norms, cand);

    // exact refine (serial) + gather + loss partials
    refine_gather<<<MROWS / 4, 256, 0, stream>>>(x, codes, norms, cand, out,
                                                 out + (size_t)MROWS * DIMK, lossP);
    finalize_loss<<<1, 1024, 0, stream>>>(lossP, out + (size_t)MROWS * DIMK + MROWS);
}

// Round 12
// 254.466 us; speedup vs baseline: 1.0953x; 1.0953x over previous
//
#include <hip/hip_runtime.h>

// SimVQ: x[8,2048,512] f32, codebook[8192,512] f32, W[512,512] f32
// out = concat(quantized[16384*512], indices[16384] (as f32), commit_loss[1])
//
// Round 18 (from R17 = 278.7; d2 = 143.7 INVARIANT across 3 sync structures):
//  Theory: d2 is DS-pipe bound (per-CU): ds_read ~147k cyc + staging writes
//  ~33k + emission __shfl_xor (if ds_swizzle) ~150k of a 345k cyc budget.
//  Single change: emission butterfly shuffles -> DPP (VALU pipe, zero DS).
//  Butterfly over basis {1,2,8,15} (quad_perm 0xB1/0x4E, row_ror:8, row_mirror)
//  == same top-3 merge (associative+commutative -> any basis works).
//  Everything else byte-identical to R17 (3-deep counted-vmcnt kept, neutral).

#define DIMK  512
#define CBN   8192
#define MROWS 16384

#define SX 24.0f
#define SC 500.0f
#define INV_SS (1.0f / (SX * SC))
#define DKEY  1231
#define NSLOT 3

// ws layout (bytes)
#define WS_CODES   0UL          // 8192*512*4    = 16,777,216
#define WS_XQ      16777216UL   // 16384*512     =  8,388,608
#define WS_CQ      25165824UL   // 8192*512      =  4,194,304
#define WS_NORMS   29360128UL   // 8192*4
#define WS_CAND    29392896UL   // 16384*128*3*4 = 25,165,824
#define WS_CBH     29392896UL   // alias: cb hi (consumed before d2 writes cand)
#define WS_CBL     37781504UL   // alias: cb lo
#define WS_WH      54558720UL   // 512*512*2 = 524,288
#define WS_WL      55083008UL
#define WS_LOSSP   55607296UL   // 16384*4
// end ~55.7 MB

typedef short s16x8 __attribute__((ext_vector_type(8)));
typedef int   i32x4 __attribute__((ext_vector_type(4)));
typedef float f32x4 __attribute__((ext_vector_type(4)));

__device__ __forceinline__ unsigned short f2bf(float f) {
    unsigned u = __float_as_uint(f);
    unsigned r = u + 0x7FFFu + ((u >> 16) & 1u);   // RTNE
    return (unsigned short)(r >> 16);
}
__device__ __forceinline__ float bf2f(unsigned short h) {
    return __uint_as_float(((unsigned)h) << 16);
}
__device__ __forceinline__ void load_lds16(const void* g, void* l) {
    __builtin_amdgcn_global_load_lds((const __attribute__((address_space(1))) void*)g,
                                     (__attribute__((address_space(3))) void*)l,
                                     16, 0, 0);
}
__device__ __forceinline__ signed char q8(float v, float s) {
    return (signed char)__float2int_rn(fminf(fmaxf(v * s, -127.0f), 127.0f));
}

// counted-vmcnt barrier (raw barrier; __syncthreads would drain vmcnt(0))
#define WAIT_BAR(N)                                              \
    do {                                                         \
        asm volatile("s_waitcnt vmcnt(" #N ")" ::: "memory");    \
        __builtin_amdgcn_s_barrier();                            \
        asm volatile("" ::: "memory");                           \
    } while (0)

// DPP cross-lane (VALU pipe, no DS): lane reads row-lane per ctrl.
// 0xB1 = quad_perm(1,0,3,2) = xor1; 0x4E = quad_perm(2,3,0,1) = xor2;
// 0x128 = row_ror:8 = xor8; 0x140 = row_mirror = xor15 (within 16-lane row).
#define DPPX(v, CTRL) \
    ((unsigned)__builtin_amdgcn_update_dpp(0, (int)(v), CTRL, 0xF, 0xF, true))

// ---------- fused prep: quant_x + split(cb) + split(W) + norms zero ----------
__global__ __launch_bounds__(256) void prep(
        const float* __restrict__ x, const float* __restrict__ cb, const float* __restrict__ W,
        signed char* __restrict__ xq,
        unsigned short* __restrict__ cbh, unsigned short* __restrict__ cbl,
        unsigned short* __restrict__ wh, unsigned short* __restrict__ wl,
        float* __restrict__ norms) {
    const int b = blockIdx.x;
    const int t = threadIdx.x;
    if (b < 8192) {
        const int i = b * 256 + t;
        float4 v = ((const float4*)x)[i];
        char4 c;
        c.x = q8(v.x, SX); c.y = q8(v.y, SX); c.z = q8(v.z, SX); c.w = q8(v.w, SX);
        ((char4*)xq)[i] = c;
    } else if (b < 12288) {
        const int i = (b - 8192) * 256 + t;
        float4 v = ((const float4*)cb)[i];
        ushort4 h, l;
        h.x = f2bf(v.x); l.x = f2bf(v.x - bf2f(h.x));
        h.y = f2bf(v.y); l.y = f2bf(v.y - bf2f(h.y));
        h.z = f2bf(v.z); l.z = f2bf(v.z - bf2f(h.z));
        h.w = f2bf(v.w); l.w = f2bf(v.w - bf2f(h.w));
        ((ushort4*)cbh)[i] = h;
        ((ushort4*)cbl)[i] = l;
    } else if (b < 12544) {
        const int i = (b - 12288) * 256 + t;
        float4 v = ((const float4*)W)[i];
        ushort4 h, l;
        h.x = f2bf(v.x); l.x = f2bf(v.x - bf2f(h.x));
        h.y = f2bf(v.y); l.y = f2bf(v.y - bf2f(h.y));
        h.z = f2bf(v.z); l.z = f2bf(v.z - bf2f(h.z));
        h.w = f2bf(v.w); l.w = f2bf(v.w - bf2f(h.w));
        ((ushort4*)wh)[i] = h;
        ((ushort4*)wl)[i] = l;
    } else {
        const int i = (b - 12544) * 256 + t;   // 0..8191
        norms[i] = 0.0f;
    }
}

// ------ codes = cb @ W^T via bf16 hi/lo 3-pass MFMA; emit f32 + i8 + norms ------
// grid (64,4), 512 thr = 8 waves (wm 0..3 x wn 0..1), wave tile 32x64, acc[2][4].
// Swizzled LDS, 3-deep counted-vmcnt pipeline (16 K-steps of 32). [R17]
__global__ __launch_bounds__(512) void codes_mfma(
        const unsigned short* __restrict__ Ah_g, const unsigned short* __restrict__ Al_g,
        const unsigned short* __restrict__ Bh_g, const unsigned short* __restrict__ Bl_g,
        float* __restrict__ C, signed char* __restrict__ Cq, float* __restrict__ Norms) {
    __shared__ __align__(16) unsigned short Ahi[3][128 * 32];
    __shared__ __align__(16) unsigned short Alo[3][128 * 32];
    __shared__ __align__(16) unsigned short Bhi[3][128 * 32];
    __shared__ __align__(16) unsigned short Blo[3][128 * 32];

    const int t    = threadIdx.x;
    const int w    = t >> 6;
    const int lane = t & 63;
    const int quad = lane >> 4;
    const int l16  = lane & 15;
    const int wm   = w & 3, wn = w >> 2;
    const int rowBase = blockIdx.x * 128;
    const int colBase = blockIdx.y * 128;

    f32x4 acc[2][4];
    #pragma unroll
    for (int i = 0; i < 2; ++i)
        #pragma unroll
        for (int j = 0; j < 4; ++j)
            acc[i][j] = (f32x4)(0.0f);

    const int mr = t >> 2;                             // 0..127
    const int kq = ((t & 3) ^ ((t >> 3) & 3)) * 8;     // swizzled source chunk (ushorts)
    const size_t gxa = (size_t)(rowBase + mr) * DIMK + kq;
    const size_t gca = (size_t)(colBase + mr) * DIMK + kq;
    const int l0 = w * 512;                            // wave-uniform LDS ushort base

    const int swz8 = (quad ^ ((l16 >> 1) & 3)) * 8;    // swizzled read chunk (ushorts)

#define CODES_STAGE(B, K0)                                     \
    do {                                                       \
        load_lds16(Ah_g + gxa + (K0), &Ahi[B][l0]);            \
        load_lds16(Al_g + gxa + (K0), &Alo[B][l0]);            \
        load_lds16(Bh_g + gca + (K0), &Bhi[B][l0]);            \
        load_lds16(Bl_g + gca + (K0), &Blo[B][l0]);            \
    } while (0)

#define CODES_COMPUTE(CUR)                                                                         \
    do {                                                                                           \
        s16x8 ah[2], al[2], bh[4], bl[4];                                                          \
        _Pragma("unroll")                                                                          \
        for (int i = 0; i < 2; ++i) {                                                              \
            const int m = wm * 32 + i * 16 + l16;                                                  \
            ah[i] = *(const s16x8*)&Ahi[CUR][m * 32 + swz8];                                       \
            al[i] = *(const s16x8*)&Alo[CUR][m * 32 + swz8];                                       \
        }                                                                                          \
        _Pragma("unroll")                                                                          \
        for (int j = 0; j < 4; ++j) {                                                              \
            const int n = wn * 64 + j * 16 + l16;                                                  \
            bh[j] = *(const s16x8*)&Bhi[CUR][n * 32 + swz8];                                       \
            bl[j] = *(const s16x8*)&Blo[CUR][n * 32 + swz8];                                       \
        }                                                                                          \
        _Pragma("unroll")                                                                          \
        for (int i = 0; i < 2; ++i)                                                                \
            _Pragma("unroll")                                                                      \
            for (int j = 0; j < 4; ++j) {                                                          \
                acc[i][j] = __builtin_amdgcn_mfma_f32_16x16x32_bf16(ah[i], bh[j], acc[i][j], 0, 0, 0); \
                acc[i][j] = __builtin_amdgcn_mfma_f32_16x16x32_bf16(ah[i], bl[j], acc[i][j], 0, 0, 0); \
                acc[i][j] = __builtin_amdgcn_mfma_f32_16x16x32_bf16(al[i], bh[j], acc[i][j], 0, 0, 0); \
            }                                                                                      \
    } while (0)

    CODES_STAGE(0, 0);
    CODES_STAGE(1, 32);
    WAIT_BAR(4);

    CODES_STAGE(2,  64); CODES_COMPUTE(0); WAIT_BAR(4);
    CODES_STAGE(0,  96); CODES_COMPUTE(1); WAIT_BAR(4);
    CODES_STAGE(1, 128); CODES_COMPUTE(2); WAIT_BAR(4);
    CODES_STAGE(2, 160); CODES_COMPUTE(0); WAIT_BAR(4);
    CODES_STAGE(0, 192); CODES_COMPUTE(1); WAIT_BAR(4);
    CODES_STAGE(1, 224); CODES_COMPUTE(2); WAIT_BAR(4);
    CODES_STAGE(2, 256); CODES_COMPUTE(0); WAIT_BAR(4);
    CODES_STAGE(0, 288); CODES_COMPUTE(1); WAIT_BAR(4);
    CODES_STAGE(1, 320); CODES_COMPUTE(2); WAIT_BAR(4);
    CODES_STAGE(2, 352); CODES_COMPUTE(0); WAIT_BAR(4);
    CODES_STAGE(0, 384); CODES_COMPUTE(1); WAIT_BAR(4);
    CODES_STAGE(1, 416); CODES_COMPUTE(2); WAIT_BAR(4);
    CODES_STAGE(2, 448); CODES_COMPUTE(0); WAIT_BAR(4);
    CODES_STAGE(0, 480); CODES_COMPUTE(1); WAIT_BAR(4);
    CODES_COMPUTE(2);                   WAIT_BAR(0);
    CODES_COMPUTE(0);
#undef CODES_STAGE
#undef CODES_COMPUTE

    // epilogue: C/D layout col = j*16+l16, row = i*16+quad*4+r
    #pragma unroll
    for (int i = 0; i < 2; ++i) {
        #pragma unroll
        for (int r = 0; r < 4; ++r) {
            const int row = rowBase + wm * 32 + i * 16 + quad * 4 + r;
            float nsum = 0.0f;
            #pragma unroll
            for (int j = 0; j < 4; ++j) {
                const int col = colBase + wn * 64 + j * 16 + l16;
                const float v = acc[i][j][r];
                C[(size_t)row * DIMK + col] = v;
                Cq[(size_t)row * DIMK + col] = q8(v, SC);
                nsum = fmaf(v, v, nsum);
            }
            nsum += __shfl_xor(nsum, 1, 64);
            nsum += __shfl_xor(nsum, 2, 64);
            nsum += __shfl_xor(nsum, 4, 64);
            nsum += __shfl_xor(nsum, 8, 64);
            if (l16 == 0) atomicAdd(&Norms[row], nsum);
        }
    }
}

// ---------- i8 distance GEMM (MFMA 16x16x64) + branch-free top-3 emission ----------
// grid: (MROWS/128, CBN/128), 512 threads = 8 waves (4x2), wave tile 32x64 (acc 2x4).
// Swizzled LDS, 3-deep counted-vmcnt pipeline, setprio on MFMA. [R17]
// Emission butterfly now ALL-DPP (VALU pipe, no DS): basis {1,2,8,15}.
__global__ __launch_bounds__(512, 6) void d2_argmin_i8(
        const signed char* __restrict__ Xq,
        const signed char* __restrict__ Cq,
        const float* __restrict__ Norms,
        unsigned* __restrict__ Cand) {
    __shared__ __align__(16) signed char Ash[3][128 * 64];
    __shared__ __align__(16) signed char Bsh[3][128 * 64];

    const int t    = threadIdx.x;
    const int w    = t >> 6;
    const int lane = t & 63;
    const int quad = lane >> 4;
    const int l16  = lane & 15;
    const int wm   = w & 3, wn = w >> 2;
    const int rowBase = blockIdx.x * 128;
    const int colBase = blockIdx.y * 128;

    i32x4 acc[2][4];
    #pragma unroll
    for (int i = 0; i < 2; ++i)
        #pragma unroll
        for (int j = 0; j < 4; ++j)
            acc[i][j] = (i32x4)(0);

    const int mr  = t >> 2;                              // 0..127
    const int kcs = ((t & 3) ^ ((t >> 3) & 3)) * 16;     // swizzled source chunk (bytes)
    const size_t gxa = (size_t)(rowBase + mr) * DIMK + kcs;
    const size_t gca = (size_t)(colBase + mr) * DIMK + kcs;
    const int lb = w * 1024;            // wave-uniform LDS byte base

    const int swz  = (quad ^ ((l16 >> 1) & 3)) * 16;
    const int aoff = (wm * 32 + l16) * 64 + swz;
    const int boff = (wn * 64 + l16) * 64 + swz;

    // key bias per column group: nq = norm*4096 + 65536
    float nq[4];
    #pragma unroll
    for (int j = 0; j < 4; ++j)
        nq[j] = fmaf(Norms[colBase + wn * 64 + j * 16 + l16], 4096.0f, 65536.0f);

#define D2_STAGE(B, K0)                                        \
    do {                                                       \
        load_lds16(Xq + gxa + (K0), &Ash[B][lb]);              \
        load_lds16(Cq + gca + (K0), &Bsh[B][lb]);              \
    } while (0)

#define D2_COMPUTE(CUR)                                                                            \
    do {                                                                                           \
        i32x4 af0 = *(const i32x4*)&Ash[CUR][aoff];                                                \
        i32x4 af1 = *(const i32x4*)&Ash[CUR][aoff + 1024];                                         \
        __builtin_amdgcn_s_setprio(1);                                                             \
        _Pragma("unroll")                                                                          \
        for (int j = 0; j < 4; ++j) {                                                              \
            const i32x4 bfj = *(const i32x4*)&Bsh[CUR][boff + j * 1024];                           \
            acc[0][j] = __builtin_amdgcn_mfma_i32_16x16x64_i8(af0, bfj, acc[0][j], 0, 0, 0);       \
            acc[1][j] = __builtin_amdgcn_mfma_i32_16x16x64_i8(af1, bfj, acc[1][j], 0, 0, 0);       \
        }                                                                                          \
        __builtin_amdgcn_s_setprio(0);                                                             \
    } while (0)

    D2_STAGE(0, 0);
    D2_STAGE(1, 64);
    WAIT_BAR(2);

    D2_STAGE(2, 128); D2_COMPUTE(0); WAIT_BAR(2);
    D2_STAGE(0, 192); D2_COMPUTE(1); WAIT_BAR(2);
    D2_STAGE(1, 256); D2_COMPUTE(2); WAIT_BAR(2);
    D2_STAGE(2, 320); D2_COMPUTE(0); WAIT_BAR(2);
    D2_STAGE(0, 384); D2_COMPUTE(1); WAIT_BAR(2);
    D2_STAGE(1, 448); D2_COMPUTE(2); WAIT_BAR(2);
    D2_COMPUTE(0);                   WAIT_BAR(0);
    D2_COMPUTE(1);
#undef D2_STAGE
#undef D2_COMPUTE

    // ---- branch-free top-3 per (row, 64-col subtile), ALL-DPP merge ----
    const unsigned colG = colBase + wn * 64 + l16;
    const int subtile = blockIdx.y * 2 + wn;
    const float C2 = -8192.0f * INV_SS;

    #pragma unroll
    for (int i = 0; i < 2; ++i) {
        #pragma unroll
        for (int r = 0; r < 4; ++r) {
            unsigned k[4];
            #pragma unroll
            for (int j = 0; j < 4; ++j) {
                const float kf = fmaf((float)acc[i][j][r], C2, nq[j]);
                int ki = (int)kf;
                ki = ki < 0 ? 0 : ki;
                ki = ki > 524287 ? 524287 : ki;
                k[j] = ((unsigned)ki << 13) | (colG + j * 16);
            }
            unsigned lo01 = min(k[0], k[1]), hi01 = max(k[0], k[1]);
            unsigned lo23 = min(k[2], k[3]), hi23 = max(k[2], k[3]);
            unsigned a0 = min(lo01, lo23);
            unsigned m  = max(lo01, lo23);
            unsigned tt = min(hi01, hi23);
            unsigned a1 = min(m, tt);
            unsigned a2 = max(m, tt);
            // butterfly over basis {1,2,8,15} — each level one DPP per value
            // (top-3 merge is associative+commutative, any basis of (Z/2)^4 works)
#define MERGE_LVL(CTRL)                                           \
            do {                                                  \
                const unsigned b0 = DPPX(a0, CTRL);               \
                const unsigned b1 = DPPX(a1, CTRL);               \
                const unsigned b2 = DPPX(a2, CTRL);               \
                const unsigned M0 = max(a0, b0);                  \
                const unsigned m1 = min(a1, b1);                  \
                a2 = min(max(m1, M0), min(a2, b2));               \
                a1 = min(M0, m1);                                 \
                a0 = min(a0, b0);                                 \
            } while (0)
            MERGE_LVL(0xB1);    // xor1  (quad_perm 1,0,3,2)
            MERGE_LVL(0x4E);    // xor2  (quad_perm 2,3,0,1)
            MERGE_LVL(0x128);   // xor8  (row_ror:8)
            MERGE_LVL(0x140);   // xor15 (row_mirror)
#undef MERGE_LVL
            if (l16 == 0) {
                const int row = rowBase + wm * 32 + i * 16 + quad * 4 + r;
                unsigned* slot = Cand + ((size_t)row * 128 + subtile) * NSLOT;
                slot[0] = a0; slot[1] = a1; slot[2] = a2;
            }
        }
    }
}

// ---------- refine candidates exactly (f32) + gather + loss partial ----------
// [R12 serial version; plain lossP store, no atomics]
__global__ __launch_bounds__(256) void refine_gather(
        const float* __restrict__ X, const float* __restrict__ Codes,
        const float* __restrict__ Norms, const unsigned* __restrict__ Cand,
        float* __restrict__ outQ, float* __restrict__ outIdx,
        float* __restrict__ lossP) {
    const int t    = threadIdx.x;
    const int w    = t >> 6;
    const int lane = t & 63;
    const int row  = blockIdx.x * 4 + w;

    const unsigned* cp = Cand + (size_t)row * 128 * NSLOT + lane * 6;
    unsigned sl[6];
    #pragma unroll
    for (int s = 0; s < 6; ++s) sl[s] = cp[s];

    unsigned mn = sl[0];
    #pragma unroll
    for (int s = 1; s < 6; ++s) mn = min(mn, sl[s]);
    #pragma unroll
    for (int mask = 1; mask < 64; mask <<= 1)
        mn = min(mn, (unsigned)__shfl((int)mn, lane ^ mask, 64));
    const unsigned thrp = (((mn >> 13) + DKEY) << 13) | 0x1FFFu;

    const float4 xa = *(const float4*)(X + (size_t)row * DIMK + lane * 8);
    const float4 xb = *(const float4*)(X + (size_t)row * DIMK + lane * 8 + 4);

    float bestD = __builtin_inff();
    unsigned bestIdx = 0xFFFFFFFFu;

    #pragma unroll
    for (int s = 0; s < 6; ++s) {
        unsigned long long bm = __ballot(sl[s] <= thrp);
        while (bm) {
            const int src = __ffsll(bm) - 1;
            bm &= bm - 1;
            const unsigned sv = (unsigned)__shfl((int)sl[s], src, 64);
            const unsigned idx = sv & 0x1FFFu;
            const float4 ca = *(const float4*)(Codes + (size_t)idx * DIMK + lane * 8);
            const float4 cbv = *(const float4*)(Codes + (size_t)idx * DIMK + lane * 8 + 4);
            float s2 = xa.x * ca.x + xa.y * ca.y + xa.z * ca.z + xa.w * ca.w
                     + xb.x * cbv.x + xb.y * cbv.y + xb.z * cbv.z + xb.w * cbv.w;
            #pragma unroll
            for (int mm = 1; mm < 64; mm <<= 1) s2 += __shfl_xor(s2, mm, 64);
            const float d2 = fmaf(-2.0f, s2, Norms[idx]);
            if (d2 < bestD || (d2 == bestD && idx < bestIdx)) { bestD = d2; bestIdx = idx; }
        }
    }

    const float4 qa = *(const float4*)(Codes + (size_t)bestIdx * DIMK + lane * 8);
    const float4 qb = *(const float4*)(Codes + (size_t)bestIdx * DIMK + lane * 8 + 4);
    *(float4*)(outQ + (size_t)row * DIMK + lane * 8) = qa;
    *(float4*)(outQ + (size_t)row * DIMK + lane * 8 + 4) = qb;
    float dx0 = xa.x - qa.x, dx1 = xa.y - qa.y, dx2 = xa.z - qa.z, dx3 = xa.w - qa.w;
    float dy0 = xb.x - qb.x, dy1 = xb.y - qb.y, dy2 = xb.z - qb.z, dy3 = xb.w - qb.w;
    float s = dx0 * dx0 + dx1 * dx1 + dx2 * dx2 + dx3 * dx3
            + dy0 * dy0 + dy1 * dy1 + dy2 * dy2 + dy3 * dy3;
    #pragma unroll
    for (int off = 32; off > 0; off >>= 1) s += __shfl_down(s, off);
    if (lane == 0) {
        lossP[row] = s;
        outIdx[row] = (float)bestIdx;
    }
}

// ---------- finalize: 1024 thr, 4 parallel float4 loads/thread ----------
__global__ __launch_bounds__(1024) void finalize_loss(const float* __restrict__ lossPartials,
                                                      float* __restrict__ outLoss) {
    const int t = threadIdx.x;
    const float4* p = (const float4*)lossPartials;   // 4096 float4s
    const float4 a = p[t];
    const float4 b = p[t + 1024];
    const float4 c = p[t + 2048];
    const float4 d = p[t + 3072];
    float s = (a.x + a.y + a.z + a.w) + (b.x + b.y + b.z + b.w)
            + (c.x + c.y + c.z + c.w) + (d.x + d.y + d.z + d.w);
    #pragma unroll
    for (int off = 32; off > 0; off >>= 1) s += __shfl_down(s, off);
    __shared__ float red[16];
    if ((t & 63) == 0) red[t >> 6] = s;
    __syncthreads();
    if (t < 64) {
        float v = (t < 16) ? red[t] : 0.0f;
        v += __shfl_down(v, 8, 64);
        v += __shfl_down(v, 4, 64);
        v += __shfl_down(v, 2, 64);
        v += __shfl_down(v, 1, 64);
        if (t == 0)
            *outLoss = v * (1.0f / (float)((size_t)MROWS * DIMK));
    }
}

extern "C" void kernel_launch(void* const* d_in, const int* in_sizes, int n_in,
                              void* d_out, int out_size, void* d_ws, size_t ws_size,
                              hipStream_t stream) {
    const float* x  = (const float*)d_in[0];
    const float* cb = (const float*)d_in[1];
    const float* W  = (const float*)d_in[2];
    float* out = (float*)d_out;

    char* ws = (char*)d_ws;
    float* codes          = (float*)(ws + WS_CODES);
    signed char* xq       = (signed char*)(ws + WS_XQ);
    signed char* cq       = (signed char*)(ws + WS_CQ);
    float* norms          = (float*)(ws + WS_NORMS);
    unsigned* cand        = (unsigned*)(ws + WS_CAND);
    unsigned short* cbh   = (unsigned short*)(ws + WS_CBH);   // aliases cand
    unsigned short* cbl   = (unsigned short*)(ws + WS_CBL);   // aliases cand
    unsigned short* wh    = (unsigned short*)(ws + WS_WH);
    unsigned short* wl    = (unsigned short*)(ws + WS_WL);
    float* lossP          = (float*)(ws + WS_LOSSP);

    // fused prep: x->i8, cb/W->bf16 hi/lo, norms zero
    prep<<<12576, 256, 0, stream>>>(x, cb, W, xq, cbh, cbl, wh, wl, norms);

    // codes = cb @ W^T (3-pass hi/lo MFMA, 3-deep counted-vmcnt pipeline)
    codes_mfma<<<dim3(CBN / 128, DIMK / 128), 512, 0, stream>>>(cbh, cbl, wh, wl, codes, cq, norms);

    // i8 MFMA distance + top-3 emission (DPP merge, no DS shuffles)
    d2_argmin_i8<<<dim3(MROWS / 128, CBN / 128), 512, 0, stream>>>(xq, cq, norms, cand);

    // exact refine (serial) + gather + loss partials
    refine_gather<<<MROWS / 4, 256, 0, stream>>>(x, codes, norms, cand, out,
                                                 out + (size_t)MROWS * DIMK, lossP);
    finalize_loss<<<1, 1024, 0, stream>>>(lossP, out + (size_t)MROWS * DIMK + MROWS);
}